// Round 1
// baseline (724.090 us; speedup 1.0000x reference)
//
#include <hip/hip_runtime.h>
#include <math.h>

#define N_ITEMS 7000
#define N_NODES 37000
#define N_USERS 30000
#define DIM     128
#define NREL    10
#define NBASES  8
#define BATCH   512
#define CTXL    100

// ---- workspace layout (element offsets, 4 bytes each) ----
#define OFF_ACC   0                                   // N_USERS*DIM floats (user aggregates)
#define OFF_ISUM  (OFF_ACC  + N_USERS * DIM)          // N_ITEMS*DIM floats
#define OFF_CNT   (OFF_ISUM + N_ITEMS * DIM)          // N_NODES*NREL ints -> later floats (1/cnt)
#define OFF_ICNT  (OFF_CNT  + N_NODES * NREL)         // N_ITEMS ints
#define ZERO_ELEMS (OFF_ICNT + N_ITEMS)               // everything before here must be zeroed
#define OFF_WC    ZERO_ELEMS                          // NREL*N_ITEMS*DIM floats (combined basis)
#define OFF_MEAN  (OFF_WC   + NREL * N_ITEMS * DIM)   // N_ITEMS*DIM floats
#define OFF_SCORE (OFF_MEAN + N_ITEMS * DIM)          // N_ITEMS floats
#define TOTAL_ELEMS (OFF_SCORE + N_ITEMS)             // ~15.0M elems = ~60 MB

// ---------------- reductions (128-thread block = 2 waves) ----------------
__device__ __forceinline__ float wave_sum(float v) {
#pragma unroll
  for (int o = 1; o < 64; o <<= 1) v += __shfl_xor(v, o, 64);
  return v;
}
__device__ __forceinline__ float wave_max(float v) {
#pragma unroll
  for (int o = 1; o < 64; o <<= 1) v = fmaxf(v, __shfl_xor(v, o, 64));
  return v;
}
__device__ __forceinline__ float block_sum_128(float v, float* sred) {
  v = wave_sum(v);
  __syncthreads();
  if ((threadIdx.x & 63) == 0) sred[threadIdx.x >> 6] = v;
  __syncthreads();
  return sred[0] + sred[1];
}
__device__ __forceinline__ float block_max_128(float v, float* sred) {
  v = wave_max(v);
  __syncthreads();
  if ((threadIdx.x & 63) == 0) sred[threadIdx.x >> 6] = v;
  __syncthreads();
  return fmaxf(sred[0], sred[1]);
}

// ---------------- kernel 1: Wc[r,i,:] = sum_b comp[r,b]*basis[b,i,:] ----------------
__global__ __launch_bounds__(DIM) void k_combine(const float* __restrict__ basis,
                                                 const float* __restrict__ comp,
                                                 float* __restrict__ Wc) {
  int i = blockIdx.x;
  int d = threadIdx.x;
  size_t base = (size_t)i * DIM + d;
  float bb[NBASES];
#pragma unroll
  for (int b = 0; b < NBASES; ++b)
    bb[b] = basis[(size_t)b * N_NODES * DIM + base];
#pragma unroll
  for (int r = 0; r < NREL; ++r) {
    float s = 0.f;
#pragma unroll
    for (int b = 0; b < NBASES; ++b) s = fmaf(comp[r * NBASES + b], bb[b], s);
    Wc[((size_t)r * N_ITEMS + i) * DIM + d] = s;
  }
}

// ---------------- kernel 2: per-(dst,rel) counts + per-item degrees ----------------
__global__ __launch_bounds__(256) void k_count(const int* __restrict__ ei,
                                               const int* __restrict__ et, int E,
                                               int* __restrict__ cnt,
                                               int* __restrict__ icnt) {
  int e = blockIdx.x * 256 + threadIdx.x;
  if (e >= E) return;
  int s = ei[e];
  int u = ei[E + e];
  int t = et[e];
  atomicAdd(&cnt[u * NREL + t], 1);
  atomicAdd(&icnt[s], 1);
}

// ---------------- kernel 3: cnt -> 1/cnt (in place, reinterpreted float) ----------------
__global__ __launch_bounds__(256) void k_invcnt(int* __restrict__ cnt, int n) {
  int j = blockIdx.x * 256 + threadIdx.x;
  if (j >= n) return;
  int c = cnt[j];
  float w = (c > 0) ? (1.0f / (float)c) : 0.0f;
  ((float*)cnt)[j] = w;
}

// ---------------- kernel 4: per-edge scatter into user accumulators ----------------
__global__ __launch_bounds__(256) void k_scatter(const int* __restrict__ ei,
                                                 const int* __restrict__ et, int E,
                                                 const float* __restrict__ winv,
                                                 const float* __restrict__ Wc,
                                                 float* __restrict__ acc) {
  int d = threadIdx.x & (DIM - 1);
  int slot = (blockIdx.x << 1) | (threadIdx.x >> 7);
  int stride = gridDim.x << 1;
  for (int e = slot; e < E; e += stride) {
    int s = ei[e];
    int u = ei[E + e];
    int t = et[e];
    float w = winv[u * NREL + t];  // >= 1 edge exists, so w = 1/cnt
    float v = Wc[((size_t)t * N_ITEMS + s) * DIM + d];
    atomicAdd(&acc[(size_t)(u - N_ITEMS) * DIM + d], w * v);
  }
}

// ---------------- kernel 5: per-edge gather node_emb[dst] into item sums ----------------
__global__ __launch_bounds__(256) void k_itemsum(const int* __restrict__ ei, int E,
                                                 const float* __restrict__ root,
                                                 const float* __restrict__ acc,
                                                 float* __restrict__ isum) {
  int d = threadIdx.x & (DIM - 1);
  int slot = (blockIdx.x << 1) | (threadIdx.x >> 7);
  int stride = gridDim.x << 1;
  for (int e = slot; e < E; e += stride) {
    int s = ei[e];
    int u = ei[E + e];
    float v = root[(size_t)u * DIM + d] + acc[(size_t)(u - N_ITEMS) * DIM + d];
    atomicAdd(&isum[(size_t)s * DIM + d], v);
  }
}

// ---------------- kernel 6: item means + per-item attention logit ----------------
__global__ __launch_bounds__(DIM) void k_meanscore(const float* __restrict__ isum,
                                                   const int* __restrict__ icnt,
                                                   const float* __restrict__ bias,
                                                   const float* __restrict__ attn_a,
                                                   const float* __restrict__ attn_b,
                                                   float* __restrict__ mean,
                                                   float* __restrict__ score) {
  __shared__ float sm[DIM];
  __shared__ float sred[2];
  int i = blockIdx.x;
  int d = threadIdx.x;
  int c = icnt[i];
  float m = (c > 0) ? (isum[(size_t)i * DIM + d] / (float)c + bias[d]) : 0.0f;
  mean[(size_t)i * DIM + d] = m;
  sm[d] = m;
  __syncthreads();
  float z = 0.f;
#pragma unroll 8
  for (int k = 0; k < DIM; ++k) z = fmaf(sm[k], attn_a[k * DIM + d], z);
  float v = tanhf(z) * attn_b[d];
  float tot = block_sum_128(v, sred);
  if (d == 0) score[i] = (c > 0) ? tot : -1e9f;  // fold item_has mask into logit
}

// ---------------- kernel 7: per-sample pooling + all projections ----------------
__global__ __launch_bounds__(DIM) void k_batch(const int* __restrict__ ctx0,
                                               const int* __restrict__ ctx1,
                                               const float* __restrict__ mean,
                                               const float* __restrict__ score,
                                               const float* __restrict__ fc1_w,
                                               const float* __restrict__ fc1_b,
                                               const float* __restrict__ fc2_w,
                                               const float* __restrict__ fc2_b,
                                               const float* __restrict__ efc1_w,
                                               const float* __restrict__ efc1_b,
                                               const float* __restrict__ efc2_w,
                                               const float* __restrict__ efc2_b,
                                               float* __restrict__ out) {
  __shared__ float shv[2 * DIM];
  __shared__ float shw[DIM];
  __shared__ int shi[DIM];
  __shared__ float shp[2][DIM];
  __shared__ float sred[2];
  int b = blockIdx.x;
  int t = threadIdx.x;

  for (int c = 0; c < 2; ++c) {
    const int* cx = (c == 0 ? ctx0 : ctx1) + (size_t)b * CTXL;
    int id = -1;
    float e = -3.0e38f;
    if (t < CTXL) {
      id = cx[t];
      e = (id >= 0) ? score[id] : -1e9f;  // score already -1e9 for degree-0 items
    }
    float m = block_max_128(e, sred);
    float ex = (t < CTXL) ? expf(e - m) : 0.f;
    float ssum = block_sum_128(ex, sred);
    float w = (t < CTXL && id >= 0) ? (ex / ssum) : 0.f;
    shw[t] = w;
    shi[t] = (id >= 0) ? id : 0;
    __syncthreads();

    // pooled[d] = sum_l w_l * mean[idx_l, d]
    float pool = 0.f;
    for (int l = 0; l < CTXL; ++l) {
      float wl = shw[l];
      if (wl != 0.f) pool = fmaf(wl, mean[(size_t)shi[l] * DIM + t], pool);
    }
    __syncthreads();
    shv[t] = pool;
    __syncthreads();

    // fc1 + relu
    float z = fc1_b[t];
#pragma unroll 8
    for (int k = 0; k < DIM; ++k) z = fmaf(shv[k], fc1_w[k * DIM + t], z);
    z = fmaxf(z, 0.f);
    __syncthreads();
    shv[t] = z;
    __syncthreads();

    // fc2 + relu
    float z2 = fc2_b[t];
#pragma unroll 8
    for (int k = 0; k < DIM; ++k) z2 = fmaf(shv[k], fc2_w[k * DIM + t], z2);
    z2 = fmaxf(z2, 0.f);
    shp[c][t] = z2;
    out[(size_t)(1 + c) * BATCH * DIM + (size_t)b * DIM + t] = z2;  // p_init / p_resp
    __syncthreads();
  }

  // profile = project(concat(p_init, p_resp))
  shv[t] = shp[0][t];
  shv[DIM + t] = shp[1][t];
  __syncthreads();
  float z = efc1_b[t];
#pragma unroll 8
  for (int k = 0; k < 2 * DIM; ++k) z = fmaf(shv[k], efc1_w[k * DIM + t], z);
  z = fmaxf(z, 0.f);
  __syncthreads();
  shv[t] = z;
  __syncthreads();
  float z2 = efc2_b[t];
#pragma unroll 8
  for (int k = 0; k < DIM; ++k) z2 = fmaf(shv[k], efc2_w[k * DIM + t], z2);
  z2 = fmaxf(z2, 0.f);
  out[(size_t)b * DIM + t] = z2;  // profile
}

// ---------------- launcher ----------------
extern "C" void kernel_launch(void* const* d_in, const int* in_sizes, int n_in,
                              void* d_out, int out_size, void* d_ws, size_t ws_size,
                              hipStream_t stream) {
  const int*   ei     = (const int*)d_in[0];
  const int*   et     = (const int*)d_in[1];
  const int*   ctx0   = (const int*)d_in[2];
  const int*   ctx1   = (const int*)d_in[3];
  const float* basis  = (const float*)d_in[4];
  const float* comp   = (const float*)d_in[5];
  const float* root   = (const float*)d_in[6];
  const float* bias   = (const float*)d_in[7];
  const float* attn_a = (const float*)d_in[8];
  const float* attn_b = (const float*)d_in[9];
  const float* fc1_w  = (const float*)d_in[10];
  const float* fc1_b  = (const float*)d_in[11];
  const float* fc2_w  = (const float*)d_in[12];
  const float* fc2_b  = (const float*)d_in[13];
  const float* efc1_w = (const float*)d_in[14];
  const float* efc1_b = (const float*)d_in[15];
  const float* efc2_w = (const float*)d_in[16];
  const float* efc2_b = (const float*)d_in[17];
  float* out = (float*)d_out;

  const int E = in_sizes[1];

  float* ws    = (float*)d_ws;
  float* acc   = ws + OFF_ACC;
  float* isum  = ws + OFF_ISUM;
  int*   cnt   = (int*)(ws + OFF_CNT);
  int*   icnt  = (int*)(ws + OFF_ICNT);
  float* Wc    = ws + OFF_WC;
  float* imean = ws + OFF_MEAN;
  float* score = ws + OFF_SCORE;

  // zero the accumulator region (acc, isum, cnt, icnt) in one memset
  hipMemsetAsync(d_ws, 0, (size_t)ZERO_ELEMS * sizeof(float), stream);

  k_combine<<<N_ITEMS, DIM, 0, stream>>>(basis, comp, Wc);
  k_count<<<(E + 255) / 256, 256, 0, stream>>>(ei, et, E, cnt, icnt);
  k_invcnt<<<(N_NODES * NREL + 255) / 256, 256, 0, stream>>>(cnt, N_NODES * NREL);
  k_scatter<<<8192, 256, 0, stream>>>(ei, et, E, (const float*)cnt, Wc, acc);
  k_itemsum<<<8192, 256, 0, stream>>>(ei, E, root, acc, isum);
  k_meanscore<<<N_ITEMS, DIM, 0, stream>>>(isum, icnt, bias, attn_a, attn_b, imean, score);
  k_batch<<<BATCH, DIM, 0, stream>>>(ctx0, ctx1, imean, score, fc1_w, fc1_b, fc2_w,
                                     fc2_b, efc1_w, efc1_b, efc2_w, efc2_b, out);
}

// Round 2
// 532.287 us; speedup vs baseline: 1.3603x; 1.3603x over previous
//
#include <hip/hip_runtime.h>
#include <math.h>

#define N_ITEMS 7000
#define N_NODES 37000
#define N_USERS 30000
#define DIM     128
#define NREL    10
#define NBASES  8
#define BATCH   512
#define CTXL    100
#define E_MAX   400000

// ---- workspace layout (element offsets, 4 bytes each) ----
#define OFF_CNT    0                               // N_NODES*NREL ints -> floats after invcnt
#define OFF_ICNT   (OFF_CNT + N_NODES * NREL)      // N_ITEMS ints (item degree)
#define OFF_UCNT   (OFF_ICNT + N_ITEMS)            // N_USERS ints (user degree)
#define ZERO_ELEMS (OFF_UCNT + N_USERS)            // zero everything before here (~1.6 MB)
#define OFF_ACC    ZERO_ELEMS                      // N_USERS*DIM floats (root+agg per user)
#define OFF_ICUR   (OFF_ACC + N_USERS * DIM)       // N_ITEMS ints (scan cursor)
#define OFF_UCUR   (OFF_ICUR + N_ITEMS)            // N_USERS ints
#define OFF_ICSR   (OFF_UCUR + N_USERS)            // E ints: user ids grouped by item
#define OFF_UCSR   (OFF_ICSR + E_MAX)              // E ints: (src | rel<<16) grouped by user
#define OFF_WC     (OFF_UCSR + E_MAX)              // NREL*N_ITEMS*DIM floats
#define OFF_MEAN   (OFF_WC + NREL * N_ITEMS * DIM) // N_ITEMS*DIM floats
#define OFF_SCORE  (OFF_MEAN + N_ITEMS * DIM)      // N_ITEMS floats

// ---------------- reductions (128-thread block = 2 waves) ----------------
__device__ __forceinline__ float wave_sum(float v) {
#pragma unroll
  for (int o = 1; o < 64; o <<= 1) v += __shfl_xor(v, o, 64);
  return v;
}
__device__ __forceinline__ float wave_max(float v) {
#pragma unroll
  for (int o = 1; o < 64; o <<= 1) v = fmaxf(v, __shfl_xor(v, o, 64));
  return v;
}
__device__ __forceinline__ float block_sum_128(float v, float* sred) {
  v = wave_sum(v);
  __syncthreads();
  if ((threadIdx.x & 63) == 0) sred[threadIdx.x >> 6] = v;
  __syncthreads();
  return sred[0] + sred[1];
}
__device__ __forceinline__ float block_max_128(float v, float* sred) {
  v = wave_max(v);
  __syncthreads();
  if ((threadIdx.x & 63) == 0) sred[threadIdx.x >> 6] = v;
  __syncthreads();
  return fmaxf(sred[0], sred[1]);
}

// ---------------- kernel 1: Wc[r,i,:] = sum_b comp[r,b]*basis[b,i,:] ----------------
__global__ __launch_bounds__(DIM) void k_combine(const float* __restrict__ basis,
                                                 const float* __restrict__ comp,
                                                 float* __restrict__ Wc) {
  int i = blockIdx.x;
  int d = threadIdx.x;
  size_t base = (size_t)i * DIM + d;
  float bb[NBASES];
#pragma unroll
  for (int b = 0; b < NBASES; ++b)
    bb[b] = basis[(size_t)b * N_NODES * DIM + base];
#pragma unroll
  for (int r = 0; r < NREL; ++r) {
    float s = 0.f;
#pragma unroll
    for (int b = 0; b < NBASES; ++b) s = fmaf(comp[r * NBASES + b], bb[b], s);
    Wc[((size_t)r * N_ITEMS + i) * DIM + d] = s;
  }
}

// ---------------- kernel 2: degrees + per-(dst,rel) counts ----------------
__global__ __launch_bounds__(256) void k_count(const int* __restrict__ ei,
                                               const int* __restrict__ et, int E,
                                               int* __restrict__ cnt,
                                               int* __restrict__ icnt,
                                               int* __restrict__ ucnt) {
  int e = blockIdx.x * 256 + threadIdx.x;
  if (e >= E) return;
  int s = ei[e];
  int u = ei[E + e];
  int t = et[e];
  atomicAdd(&cnt[u * NREL + t], 1);
  atomicAdd(&icnt[s], 1);
  atomicAdd(&ucnt[u - N_ITEMS], 1);
}

// ---------------- kernel 3: exclusive scans -> cursors (block0: items, block1: users) ----
__global__ __launch_bounds__(1024) void k_scan(const int* __restrict__ icnt,
                                               const int* __restrict__ ucnt,
                                               int* __restrict__ icur,
                                               int* __restrict__ ucur) {
  __shared__ int ss[1024];
  const int* in;
  int n;
  int* cur;
  if (blockIdx.x == 0) { in = icnt; n = N_ITEMS; cur = icur; }
  else                 { in = ucnt; n = N_USERS; cur = ucur; }
  int t = threadIdx.x;
  int chunk = (n + 1023) / 1024;
  int lo = t * chunk;
  int hi = lo + chunk;
  if (lo > n) lo = n;
  if (hi > n) hi = n;
  int s = 0;
  for (int i = lo; i < hi; ++i) s += in[i];
  ss[t] = s;
  __syncthreads();
  for (int o = 1; o < 1024; o <<= 1) {
    int v = (t >= o) ? ss[t - o] : 0;
    __syncthreads();
    ss[t] += v;
    __syncthreads();
  }
  int base = (t > 0) ? ss[t - 1] : 0;
  for (int i = lo; i < hi; ++i) { cur[i] = base; base += in[i]; }
}

// ---------------- kernel 4: cnt -> 1/cnt (in place, reinterpreted float) ----------------
__global__ __launch_bounds__(256) void k_invcnt(int* __restrict__ cnt, int n) {
  int j = blockIdx.x * 256 + threadIdx.x;
  if (j >= n) return;
  int c = cnt[j];
  ((float*)cnt)[j] = (c > 0) ? (1.0f / (float)c) : 0.0f;
}

// ---------------- kernel 5: fill CSR payloads ----------------
__global__ __launch_bounds__(256) void k_fill(const int* __restrict__ ei,
                                              const int* __restrict__ et, int E,
                                              int* __restrict__ icur,
                                              int* __restrict__ ucur,
                                              int* __restrict__ icsr,
                                              int* __restrict__ ucsr) {
  int e = blockIdx.x * 256 + threadIdx.x;
  if (e >= E) return;
  int s = ei[e];
  int u0 = ei[E + e] - N_ITEMS;
  int t = et[e];
  int pi = atomicAdd(&icur[s], 1);
  icsr[pi] = u0;
  int pu = atomicAdd(&ucur[u0], 1);
  ucsr[pu] = s | (t << 16);
}

// ---------------- kernel 6: per-user aggregate, no atomics ----------------
// acc[u] = root[N_ITEMS+u] + sum_e winv(u,t_e) * Wc[t_e][s_e]
__global__ __launch_bounds__(DIM) void k_useragg(const int* __restrict__ ucnt,
                                                 const int* __restrict__ ucur,
                                                 const int* __restrict__ ucsr,
                                                 const float* __restrict__ winv,
                                                 const float* __restrict__ Wc,
                                                 const float* __restrict__ root,
                                                 float* __restrict__ acc) {
  __shared__ float wrow[NREL];
  __shared__ int sedge[128];
  int u = blockIdx.x, d = threadIdx.x;
  int deg = ucnt[u];
  int base = ucur[u] - deg;  // cursor ended at segment end
  if (d < NREL) wrow[d] = winv[(size_t)(N_ITEMS + u) * NREL + d];
  float r = root[(size_t)(N_ITEMS + u) * DIM + d];
  for (int j0 = 0; j0 < deg; j0 += 128) {
    int m = deg - j0;
    if (m > 128) m = 128;
    __syncthreads();
    if (d < m) sedge[d] = ucsr[base + j0 + d];
    __syncthreads();
    for (int j = 0; j < m; ++j) {
      int p = sedge[j];
      int s = p & 0xffff, t = p >> 16;
      r = fmaf(wrow[t], Wc[((size_t)t * N_ITEMS + s) * DIM + d], r);
    }
  }
  acc[(size_t)u * DIM + d] = r;
}

// ---------------- kernel 7: per-item aggregate + mean + attention logit ----------------
__global__ __launch_bounds__(DIM) void k_itemagg(const int* __restrict__ icnt,
                                                 const int* __restrict__ icur,
                                                 const int* __restrict__ icsr,
                                                 const float* __restrict__ acc,
                                                 const float* __restrict__ bias,
                                                 const float* __restrict__ attn_a,
                                                 const float* __restrict__ attn_b,
                                                 float* __restrict__ mean,
                                                 float* __restrict__ score) {
  __shared__ int sedge[128];
  __shared__ float sm[DIM];
  __shared__ float sred[2];
  int i = blockIdx.x, d = threadIdx.x;
  int deg = icnt[i];
  int base = icur[i] - deg;
  float sum = 0.f;
  for (int j0 = 0; j0 < deg; j0 += 128) {
    int m = deg - j0;
    if (m > 128) m = 128;
    __syncthreads();
    if (d < m) sedge[d] = icsr[base + j0 + d];
    __syncthreads();
    for (int j = 0; j < m; ++j) sum += acc[(size_t)sedge[j] * DIM + d];
  }
  float mv = (deg > 0) ? (sum / (float)deg + bias[d]) : 0.f;
  mean[(size_t)i * DIM + d] = mv;
  __syncthreads();
  sm[d] = mv;
  __syncthreads();
  float z = 0.f;
#pragma unroll 8
  for (int k = 0; k < DIM; ++k) z = fmaf(sm[k], attn_a[k * DIM + d], z);
  float v = tanhf(z) * attn_b[d];
  float tot = block_sum_128(v, sred);
  if (d == 0) score[i] = (deg > 0) ? tot : -1e9f;
}

// ---------------- kernel 8: per-sample pooling + all projections ----------------
__global__ __launch_bounds__(DIM) void k_batch(const int* __restrict__ ctx0,
                                               const int* __restrict__ ctx1,
                                               const float* __restrict__ mean,
                                               const float* __restrict__ score,
                                               const float* __restrict__ fc1_w,
                                               const float* __restrict__ fc1_b,
                                               const float* __restrict__ fc2_w,
                                               const float* __restrict__ fc2_b,
                                               const float* __restrict__ efc1_w,
                                               const float* __restrict__ efc1_b,
                                               const float* __restrict__ efc2_w,
                                               const float* __restrict__ efc2_b,
                                               float* __restrict__ out) {
  __shared__ float shv[2 * DIM];
  __shared__ float shw[DIM];
  __shared__ int shi[DIM];
  __shared__ float shp[2][DIM];
  __shared__ float sred[2];
  int b = blockIdx.x;
  int t = threadIdx.x;

  for (int c = 0; c < 2; ++c) {
    const int* cx = (c == 0 ? ctx0 : ctx1) + (size_t)b * CTXL;
    int id = -1;
    float e = -3.0e38f;
    if (t < CTXL) {
      id = cx[t];
      e = (id >= 0) ? score[id] : -1e9f;
    }
    float m = block_max_128(e, sred);
    float ex = (t < CTXL) ? expf(e - m) : 0.f;
    float ssum = block_sum_128(ex, sred);
    float w = (t < CTXL && id >= 0) ? (ex / ssum) : 0.f;
    shw[t] = w;
    shi[t] = (id >= 0) ? id : 0;
    __syncthreads();

    float pool = 0.f;
    for (int l = 0; l < CTXL; ++l) {
      float wl = shw[l];
      if (wl != 0.f) pool = fmaf(wl, mean[(size_t)shi[l] * DIM + t], pool);
    }
    __syncthreads();
    shv[t] = pool;
    __syncthreads();

    float z = fc1_b[t];
#pragma unroll 8
    for (int k = 0; k < DIM; ++k) z = fmaf(shv[k], fc1_w[k * DIM + t], z);
    z = fmaxf(z, 0.f);
    __syncthreads();
    shv[t] = z;
    __syncthreads();

    float z2 = fc2_b[t];
#pragma unroll 8
    for (int k = 0; k < DIM; ++k) z2 = fmaf(shv[k], fc2_w[k * DIM + t], z2);
    z2 = fmaxf(z2, 0.f);
    shp[c][t] = z2;
    out[(size_t)(1 + c) * BATCH * DIM + (size_t)b * DIM + t] = z2;
    __syncthreads();
  }

  shv[t] = shp[0][t];
  shv[DIM + t] = shp[1][t];
  __syncthreads();
  float z = efc1_b[t];
#pragma unroll 8
  for (int k = 0; k < 2 * DIM; ++k) z = fmaf(shv[k], efc1_w[k * DIM + t], z);
  z = fmaxf(z, 0.f);
  __syncthreads();
  shv[t] = z;
  __syncthreads();
  float z2 = efc2_b[t];
#pragma unroll 8
  for (int k = 0; k < DIM; ++k) z2 = fmaf(shv[k], efc2_w[k * DIM + t], z2);
  z2 = fmaxf(z2, 0.f);
  out[(size_t)b * DIM + t] = z2;
}

// ---------------- launcher ----------------
extern "C" void kernel_launch(void* const* d_in, const int* in_sizes, int n_in,
                              void* d_out, int out_size, void* d_ws, size_t ws_size,
                              hipStream_t stream) {
  const int*   ei     = (const int*)d_in[0];
  const int*   et     = (const int*)d_in[1];
  const int*   ctx0   = (const int*)d_in[2];
  const int*   ctx1   = (const int*)d_in[3];
  const float* basis  = (const float*)d_in[4];
  const float* comp   = (const float*)d_in[5];
  const float* root   = (const float*)d_in[6];
  const float* bias   = (const float*)d_in[7];
  const float* attn_a = (const float*)d_in[8];
  const float* attn_b = (const float*)d_in[9];
  const float* fc1_w  = (const float*)d_in[10];
  const float* fc1_b  = (const float*)d_in[11];
  const float* fc2_w  = (const float*)d_in[12];
  const float* fc2_b  = (const float*)d_in[13];
  const float* efc1_w = (const float*)d_in[14];
  const float* efc1_b = (const float*)d_in[15];
  const float* efc2_w = (const float*)d_in[16];
  const float* efc2_b = (const float*)d_in[17];
  float* out = (float*)d_out;

  const int E = in_sizes[1];

  float* ws    = (float*)d_ws;
  int*   cnt   = (int*)(ws + OFF_CNT);
  int*   icnt  = (int*)(ws + OFF_ICNT);
  int*   ucnt  = (int*)(ws + OFF_UCNT);
  float* acc   = ws + OFF_ACC;
  int*   icur  = (int*)(ws + OFF_ICUR);
  int*   ucur  = (int*)(ws + OFF_UCUR);
  int*   icsr  = (int*)(ws + OFF_ICSR);
  int*   ucsr  = (int*)(ws + OFF_UCSR);
  float* Wc    = ws + OFF_WC;
  float* imean = ws + OFF_MEAN;
  float* score = ws + OFF_SCORE;

  hipMemsetAsync(d_ws, 0, (size_t)ZERO_ELEMS * sizeof(float), stream);

  k_combine<<<N_ITEMS, DIM, 0, stream>>>(basis, comp, Wc);
  k_count<<<(E + 255) / 256, 256, 0, stream>>>(ei, et, E, cnt, icnt, ucnt);
  k_scan<<<2, 1024, 0, stream>>>(icnt, ucnt, icur, ucur);
  k_invcnt<<<(N_NODES * NREL + 255) / 256, 256, 0, stream>>>(cnt, N_NODES * NREL);
  k_fill<<<(E + 255) / 256, 256, 0, stream>>>(ei, et, E, icur, ucur, icsr, ucsr);
  k_useragg<<<N_USERS, DIM, 0, stream>>>(ucnt, ucur, ucsr, (const float*)cnt, Wc, root, acc);
  k_itemagg<<<N_ITEMS, DIM, 0, stream>>>(icnt, icur, icsr, acc, bias, attn_a, attn_b,
                                         imean, score);
  k_batch<<<BATCH, DIM, 0, stream>>>(ctx0, ctx1, imean, score, fc1_w, fc1_b, fc2_w,
                                     fc2_b, efc1_w, efc1_b, efc2_w, efc2_b, out);
}

// Round 3
// 481.327 us; speedup vs baseline: 1.5044x; 1.1059x over previous
//
#include <hip/hip_runtime.h>
#include <math.h>

typedef unsigned int uint;

#define N_ITEMS 7000
#define N_NODES 37000
#define N_USERS 30000
#define DIM     128
#define HD      64        // DIM/2, dims handled as packed pairs
#define NREL    10
#define NBASES  8
#define BATCH   512
#define CTXL    100
#define E_MAX   400000

// ---- workspace layout (4-byte element offsets) ----
#define OFF_CNT    0                               // N_USERS*NREL ints (per-(user,rel) edge count)
#define OFF_ICNT   (OFF_CNT + N_USERS * NREL)      // N_ITEMS ints
#define OFF_UCNT   (OFF_ICNT + N_ITEMS)            // N_USERS ints
#define ZERO_ELEMS (OFF_UCNT + N_USERS)            // zero up to here (~1.35 MB)
#define OFF_ICUR   ZERO_ELEMS                      // N_ITEMS ints
#define OFF_UCUR   (OFF_ICUR + N_ITEMS)            // N_USERS ints
#define OFF_ICSR   (OFF_UCUR + N_USERS)            // E ints (user idx grouped by item)
#define OFF_UCSR   (OFF_ICSR + E_MAX)              // E ints (s | rel<<16 grouped by user)
#define OFF_WC     (OFF_UCSR + E_MAX)              // NREL*N_ITEMS*HD uints (bf16x2)
#define OFF_ACC    (OFF_WC + NREL * N_ITEMS * HD)  // N_USERS*HD uints (bf16x2)
#define OFF_MEAN   (OFF_ACC + N_USERS * HD)        // N_ITEMS*HD uints (bf16x2)
#define OFF_SCORE  (OFF_MEAN + N_ITEMS * HD)       // N_ITEMS floats

// ---------------- bf16 pack/unpack (RNE) ----------------
__device__ __forceinline__ float2 bf2f(uint p) {
  float2 r;
  r.x = __uint_as_float(p << 16);
  r.y = __uint_as_float(p & 0xffff0000u);
  return r;
}
__device__ __forceinline__ uint f2bf(float x, float y) {
  uint a = __float_as_uint(x), b = __float_as_uint(y);
  a += 0x7fffu + ((a >> 16) & 1u);
  b += 0x7fffu + ((b >> 16) & 1u);
  return (a >> 16) | (b & 0xffff0000u);
}

// ---------------- single-wave reductions ----------------
__device__ __forceinline__ float wave_sum(float v) {
#pragma unroll
  for (int o = 1; o < 64; o <<= 1) v += __shfl_xor(v, o, 64);
  return v;
}
__device__ __forceinline__ float wave_max(float v) {
#pragma unroll
  for (int o = 1; o < 64; o <<= 1) v = fmaxf(v, __shfl_xor(v, o, 64));
  return v;
}

// ---------------- kernel 1: Wc[r,i,:] = sum_b comp[r,b]*basis[b,i,:]  (bf16 out) ----------
__global__ __launch_bounds__(HD) void k_combine(const float* __restrict__ basis,
                                                const float* __restrict__ comp,
                                                uint* __restrict__ Wc) {
  int i = blockIdx.x, t = threadIdx.x;
  float2 bb[NBASES];
#pragma unroll
  for (int b = 0; b < NBASES; ++b)
    bb[b] = ((const float2*)(basis + ((size_t)b * N_NODES + i) * DIM))[t];
#pragma unroll
  for (int r = 0; r < NREL; ++r) {
    float sx = 0.f, sy = 0.f;
#pragma unroll
    for (int b = 0; b < NBASES; ++b) {
      float c = comp[r * NBASES + b];
      sx = fmaf(c, bb[b].x, sx);
      sy = fmaf(c, bb[b].y, sy);
    }
    Wc[((size_t)r * N_ITEMS + i) * HD + t] = f2bf(sx, sy);
  }
}

// ---------------- kernel 2: degrees + per-(user,rel) counts ----------------
__global__ __launch_bounds__(256) void k_count(const int* __restrict__ ei,
                                               const int* __restrict__ et, int E,
                                               int* __restrict__ cnt,
                                               int* __restrict__ icnt,
                                               int* __restrict__ ucnt) {
  int e = blockIdx.x * 256 + threadIdx.x;
  if (e >= E) return;
  int s = ei[e];
  int u0 = ei[E + e] - N_ITEMS;
  int t = et[e];
  atomicAdd(&cnt[u0 * NREL + t], 1);
  atomicAdd(&icnt[s], 1);
  atomicAdd(&ucnt[u0], 1);
}

// ---------------- kernel 3: exclusive scans -> cursors ----------------
__global__ __launch_bounds__(1024) void k_scan(const int* __restrict__ icnt,
                                               const int* __restrict__ ucnt,
                                               int* __restrict__ icur,
                                               int* __restrict__ ucur) {
  __shared__ int ss[1024];
  const int* in;
  int n;
  int* cur;
  if (blockIdx.x == 0) { in = icnt; n = N_ITEMS; cur = icur; }
  else                 { in = ucnt; n = N_USERS; cur = ucur; }
  int t = threadIdx.x;
  int chunk = (n + 1023) / 1024;
  int lo = t * chunk, hi = lo + chunk;
  if (lo > n) lo = n;
  if (hi > n) hi = n;
  int s = 0;
  for (int i = lo; i < hi; ++i) s += in[i];
  ss[t] = s;
  __syncthreads();
  for (int o = 1; o < 1024; o <<= 1) {
    int v = (t >= o) ? ss[t - o] : 0;
    __syncthreads();
    ss[t] += v;
    __syncthreads();
  }
  int base = (t > 0) ? ss[t - 1] : 0;
  for (int i = lo; i < hi; ++i) { cur[i] = base; base += in[i]; }
}

// ---------------- kernel 4: fill CSR payloads ----------------
__global__ __launch_bounds__(256) void k_fill(const int* __restrict__ ei,
                                              const int* __restrict__ et, int E,
                                              int* __restrict__ icur,
                                              int* __restrict__ ucur,
                                              int* __restrict__ icsr,
                                              int* __restrict__ ucsr) {
  int e = blockIdx.x * 256 + threadIdx.x;
  if (e >= E) return;
  int s = ei[e];
  int u0 = ei[E + e] - N_ITEMS;
  int t = et[e];
  icsr[atomicAdd(&icur[s], 1)] = u0;
  ucsr[atomicAdd(&ucur[u0], 1)] = s | (t << 16);
}

// ---------------- kernel 5: per-user aggregate (bf16 gather, bf16 out) ----------------
__global__ __launch_bounds__(HD) void k_useragg(const int* __restrict__ ucnt,
                                                const int* __restrict__ ucur,
                                                const int* __restrict__ ucsr,
                                                const int* __restrict__ cnt,
                                                const uint* __restrict__ Wc,
                                                const float* __restrict__ root,
                                                uint* __restrict__ acc) {
  __shared__ float wrow[NREL];
  __shared__ int sedge[HD];
  int u = blockIdx.x, t = threadIdx.x;
  if (t < NREL) {
    int c = cnt[u * NREL + t];
    wrow[t] = (c > 0) ? 1.0f / (float)c : 0.0f;
  }
  int deg = ucnt[u];
  int base = ucur[u] - deg;  // cursor ended at segment end
  float2 a0 = {0.f, 0.f}, a1 = {0.f, 0.f}, a2 = {0.f, 0.f}, a3 = {0.f, 0.f};
  for (int j0 = 0; j0 < deg; j0 += HD) {
    int m = deg - j0;
    if (m > HD) m = HD;
    __syncthreads();
    if (t < m) sedge[t] = ucsr[base + j0 + t];
    __syncthreads();
    int j = 0;
    for (; j + 4 <= m; j += 4) {
      int p0 = sedge[j], p1 = sedge[j + 1], p2 = sedge[j + 2], p3 = sedge[j + 3];
      uint q0 = Wc[(size_t)((p0 >> 16) * N_ITEMS + (p0 & 0xffff)) * HD + t];
      uint q1 = Wc[(size_t)((p1 >> 16) * N_ITEMS + (p1 & 0xffff)) * HD + t];
      uint q2 = Wc[(size_t)((p2 >> 16) * N_ITEMS + (p2 & 0xffff)) * HD + t];
      uint q3 = Wc[(size_t)((p3 >> 16) * N_ITEMS + (p3 & 0xffff)) * HD + t];
      float w0 = wrow[p0 >> 16], w1 = wrow[p1 >> 16];
      float w2 = wrow[p2 >> 16], w3 = wrow[p3 >> 16];
      float2 f0 = bf2f(q0), f1 = bf2f(q1), f2 = bf2f(q2), f3 = bf2f(q3);
      a0.x = fmaf(w0, f0.x, a0.x); a0.y = fmaf(w0, f0.y, a0.y);
      a1.x = fmaf(w1, f1.x, a1.x); a1.y = fmaf(w1, f1.y, a1.y);
      a2.x = fmaf(w2, f2.x, a2.x); a2.y = fmaf(w2, f2.y, a2.y);
      a3.x = fmaf(w3, f3.x, a3.x); a3.y = fmaf(w3, f3.y, a3.y);
    }
    for (; j < m; ++j) {
      int p = sedge[j];
      uint q = Wc[(size_t)((p >> 16) * N_ITEMS + (p & 0xffff)) * HD + t];
      float w = wrow[p >> 16];
      float2 f = bf2f(q);
      a0.x = fmaf(w, f.x, a0.x); a0.y = fmaf(w, f.y, a0.y);
    }
  }
  float2 r = ((const float2*)(root + (size_t)(N_ITEMS + u) * DIM))[t];
  r.x += a0.x + a1.x + a2.x + a3.x;
  r.y += a0.y + a1.y + a2.y + a3.y;
  acc[(size_t)u * HD + t] = f2bf(r.x, r.y);
}

// ---------------- kernel 6: per-item aggregate + mean + attention logit ----------------
__global__ __launch_bounds__(HD) void k_itemagg(const int* __restrict__ icnt,
                                                const int* __restrict__ icur,
                                                const int* __restrict__ icsr,
                                                const uint* __restrict__ acc,
                                                const float* __restrict__ bias,
                                                const float* __restrict__ attn_a,
                                                const float* __restrict__ attn_b,
                                                uint* __restrict__ mean,
                                                float* __restrict__ score) {
  __shared__ int sedge[HD];
  __shared__ float sm[DIM];
  int i = blockIdx.x, t = threadIdx.x;
  int deg = icnt[i];
  int base = icur[i] - deg;
  float2 a0 = {0.f, 0.f}, a1 = {0.f, 0.f}, a2 = {0.f, 0.f}, a3 = {0.f, 0.f};
  for (int j0 = 0; j0 < deg; j0 += HD) {
    int m = deg - j0;
    if (m > HD) m = HD;
    __syncthreads();
    if (t < m) sedge[t] = icsr[base + j0 + t];
    __syncthreads();
    int j = 0;
    for (; j + 4 <= m; j += 4) {
      uint q0 = acc[(size_t)sedge[j] * HD + t];
      uint q1 = acc[(size_t)sedge[j + 1] * HD + t];
      uint q2 = acc[(size_t)sedge[j + 2] * HD + t];
      uint q3 = acc[(size_t)sedge[j + 3] * HD + t];
      float2 f0 = bf2f(q0), f1 = bf2f(q1), f2 = bf2f(q2), f3 = bf2f(q3);
      a0.x += f0.x; a0.y += f0.y;
      a1.x += f1.x; a1.y += f1.y;
      a2.x += f2.x; a2.y += f2.y;
      a3.x += f3.x; a3.y += f3.y;
    }
    for (; j < m; ++j) {
      float2 f = bf2f(acc[(size_t)sedge[j] * HD + t]);
      a0.x += f.x; a0.y += f.y;
    }
  }
  float2 mv = {0.f, 0.f};
  if (deg > 0) {
    float inv = 1.0f / (float)deg;
    float2 bvec = ((const float2*)bias)[t];
    mv.x = (a0.x + a1.x + a2.x + a3.x) * inv + bvec.x;
    mv.y = (a0.y + a1.y + a2.y + a3.y) * inv + bvec.y;
  }
  mean[(size_t)i * HD + t] = f2bf(mv.x, mv.y);
  sm[2 * t] = mv.x;
  sm[2 * t + 1] = mv.y;
  __syncthreads();
  float z0 = 0.f, z1 = 0.f;
#pragma unroll 8
  for (int k = 0; k < DIM; ++k) {
    float2 w = ((const float2*)(attn_a + (size_t)k * DIM))[t];
    float h = sm[k];
    z0 = fmaf(h, w.x, z0);
    z1 = fmaf(h, w.y, z1);
  }
  float2 ab = ((const float2*)attn_b)[t];
  float v = wave_sum(tanhf(z0) * ab.x + tanhf(z1) * ab.y);
  if (t == 0) score[i] = (deg > 0) ? v : -1e9f;
}

// ---------------- kernel 7: attention pool + fc1 + fc2 (one block per (sample,side)) ----
__global__ __launch_bounds__(HD) void k_pool(const int* __restrict__ ctx0,
                                             const int* __restrict__ ctx1,
                                             const uint* __restrict__ mean,
                                             const float* __restrict__ score,
                                             const float* __restrict__ fc1_w,
                                             const float* __restrict__ fc1_b,
                                             const float* __restrict__ fc2_w,
                                             const float* __restrict__ fc2_b,
                                             float* __restrict__ out) {
  __shared__ float shw[CTXL];
  __shared__ int shi[CTXL];
  __shared__ float shv[DIM];
  int b = blockIdx.x & (BATCH - 1);
  int c = blockIdx.x >> 9;
  int t = threadIdx.x;
  const int* cx = (c == 0 ? ctx0 : ctx1) + (size_t)b * CTXL;

  int id0 = cx[t];
  float e0 = (id0 >= 0) ? score[id0] : -1e9f;
  int id1 = -1;
  float e1 = -3.0e38f;
  if (t + HD < CTXL) {
    id1 = cx[t + HD];
    e1 = (id1 >= 0) ? score[id1] : -1e9f;
  }
  float m = wave_max(fmaxf(e0, e1));
  float x0 = expf(e0 - m);
  float x1 = (t + HD < CTXL) ? expf(e1 - m) : 0.f;
  float inv = 1.0f / wave_sum(x0 + x1);
  shw[t] = (id0 >= 0) ? x0 * inv : 0.f;
  shi[t] = (id0 >= 0) ? id0 : 0;
  if (t + HD < CTXL) {
    shw[t + HD] = (id1 >= 0) ? x1 * inv : 0.f;
    shi[t + HD] = (id1 >= 0) ? id1 : 0;
  }
  __syncthreads();

  float2 a0 = {0.f, 0.f}, a1 = {0.f, 0.f}, a2 = {0.f, 0.f}, a3 = {0.f, 0.f};
#pragma unroll 5
  for (int l = 0; l < CTXL; l += 4) {
    float w0 = shw[l], w1 = shw[l + 1], w2 = shw[l + 2], w3 = shw[l + 3];
    uint q0 = mean[(size_t)shi[l] * HD + t];
    uint q1 = mean[(size_t)shi[l + 1] * HD + t];
    uint q2 = mean[(size_t)shi[l + 2] * HD + t];
    uint q3 = mean[(size_t)shi[l + 3] * HD + t];
    float2 f0 = bf2f(q0), f1 = bf2f(q1), f2 = bf2f(q2), f3 = bf2f(q3);
    a0.x = fmaf(w0, f0.x, a0.x); a0.y = fmaf(w0, f0.y, a0.y);
    a1.x = fmaf(w1, f1.x, a1.x); a1.y = fmaf(w1, f1.y, a1.y);
    a2.x = fmaf(w2, f2.x, a2.x); a2.y = fmaf(w2, f2.y, a2.y);
    a3.x = fmaf(w3, f3.x, a3.x); a3.y = fmaf(w3, f3.y, a3.y);
  }
  __syncthreads();
  shv[2 * t] = a0.x + a1.x + a2.x + a3.x;
  shv[2 * t + 1] = a0.y + a1.y + a2.y + a3.y;
  __syncthreads();

  float2 z = ((const float2*)fc1_b)[t];
#pragma unroll 8
  for (int k = 0; k < DIM; ++k) {
    float2 w = ((const float2*)(fc1_w + (size_t)k * DIM))[t];
    float h = shv[k];
    z.x = fmaf(h, w.x, z.x);
    z.y = fmaf(h, w.y, z.y);
  }
  z.x = fmaxf(z.x, 0.f);
  z.y = fmaxf(z.y, 0.f);
  __syncthreads();
  shv[2 * t] = z.x;
  shv[2 * t + 1] = z.y;
  __syncthreads();

  float2 z2 = ((const float2*)fc2_b)[t];
#pragma unroll 8
  for (int k = 0; k < DIM; ++k) {
    float2 w = ((const float2*)(fc2_w + (size_t)k * DIM))[t];
    float h = shv[k];
    z2.x = fmaf(h, w.x, z2.x);
    z2.y = fmaf(h, w.y, z2.y);
  }
  z2.x = fmaxf(z2.x, 0.f);
  z2.y = fmaxf(z2.y, 0.f);
  ((float2*)(out + (size_t)(1 + c) * BATCH * DIM + (size_t)b * DIM))[t] = z2;
}

// ---------------- kernel 8: profile = project(concat(p_init, p_resp)) ----------------
__global__ __launch_bounds__(HD) void k_profile(const float* __restrict__ efc1_w,
                                                const float* __restrict__ efc1_b,
                                                const float* __restrict__ efc2_w,
                                                const float* __restrict__ efc2_b,
                                                float* __restrict__ out) {
  __shared__ float shv[2 * DIM];
  __shared__ float sh2[DIM];
  int b = blockIdx.x, t = threadIdx.x;
  float2 p0 = ((const float2*)(out + (size_t)BATCH * DIM + (size_t)b * DIM))[t];
  float2 p1 = ((const float2*)(out + (size_t)2 * BATCH * DIM + (size_t)b * DIM))[t];
  shv[2 * t] = p0.x;
  shv[2 * t + 1] = p0.y;
  shv[DIM + 2 * t] = p1.x;
  shv[DIM + 2 * t + 1] = p1.y;
  __syncthreads();
  float2 z = ((const float2*)efc1_b)[t];
#pragma unroll 8
  for (int k = 0; k < 2 * DIM; ++k) {
    float2 w = ((const float2*)(efc1_w + (size_t)k * DIM))[t];
    float h = shv[k];
    z.x = fmaf(h, w.x, z.x);
    z.y = fmaf(h, w.y, z.y);
  }
  z.x = fmaxf(z.x, 0.f);
  z.y = fmaxf(z.y, 0.f);
  __syncthreads();
  sh2[2 * t] = z.x;
  sh2[2 * t + 1] = z.y;
  __syncthreads();
  float2 z2 = ((const float2*)efc2_b)[t];
#pragma unroll 8
  for (int k = 0; k < DIM; ++k) {
    float2 w = ((const float2*)(efc2_w + (size_t)k * DIM))[t];
    float h = sh2[k];
    z2.x = fmaf(h, w.x, z2.x);
    z2.y = fmaf(h, w.y, z2.y);
  }
  z2.x = fmaxf(z2.x, 0.f);
  z2.y = fmaxf(z2.y, 0.f);
  ((float2*)(out + (size_t)b * DIM))[t] = z2;
}

// ---------------- launcher ----------------
extern "C" void kernel_launch(void* const* d_in, const int* in_sizes, int n_in,
                              void* d_out, int out_size, void* d_ws, size_t ws_size,
                              hipStream_t stream) {
  const int*   ei     = (const int*)d_in[0];
  const int*   et     = (const int*)d_in[1];
  const int*   ctx0   = (const int*)d_in[2];
  const int*   ctx1   = (const int*)d_in[3];
  const float* basis  = (const float*)d_in[4];
  const float* comp   = (const float*)d_in[5];
  const float* root   = (const float*)d_in[6];
  const float* bias   = (const float*)d_in[7];
  const float* attn_a = (const float*)d_in[8];
  const float* attn_b = (const float*)d_in[9];
  const float* fc1_w  = (const float*)d_in[10];
  const float* fc1_b  = (const float*)d_in[11];
  const float* fc2_w  = (const float*)d_in[12];
  const float* fc2_b  = (const float*)d_in[13];
  const float* efc1_w = (const float*)d_in[14];
  const float* efc1_b = (const float*)d_in[15];
  const float* efc2_w = (const float*)d_in[16];
  const float* efc2_b = (const float*)d_in[17];
  float* out = (float*)d_out;

  const int E = in_sizes[1];

  float* ws   = (float*)d_ws;
  int*  cnt   = (int*)(ws + OFF_CNT);
  int*  icnt  = (int*)(ws + OFF_ICNT);
  int*  ucnt  = (int*)(ws + OFF_UCNT);
  int*  icur  = (int*)(ws + OFF_ICUR);
  int*  ucur  = (int*)(ws + OFF_UCUR);
  int*  icsr  = (int*)(ws + OFF_ICSR);
  int*  ucsr  = (int*)(ws + OFF_UCSR);
  uint* Wc    = (uint*)(ws + OFF_WC);
  uint* acc   = (uint*)(ws + OFF_ACC);
  uint* mean  = (uint*)(ws + OFF_MEAN);
  float* score = ws + OFF_SCORE;

  hipMemsetAsync(d_ws, 0, (size_t)ZERO_ELEMS * sizeof(float), stream);

  k_combine<<<N_ITEMS, HD, 0, stream>>>(basis, comp, Wc);
  k_count<<<(E + 255) / 256, 256, 0, stream>>>(ei, et, E, cnt, icnt, ucnt);
  k_scan<<<2, 1024, 0, stream>>>(icnt, ucnt, icur, ucur);
  k_fill<<<(E + 255) / 256, 256, 0, stream>>>(ei, et, E, icur, ucur, icsr, ucsr);
  k_useragg<<<N_USERS, HD, 0, stream>>>(ucnt, ucur, ucsr, cnt, Wc, root, acc);
  k_itemagg<<<N_ITEMS, HD, 0, stream>>>(icnt, icur, icsr, acc, bias, attn_a, attn_b,
                                        mean, score);
  k_pool<<<2 * BATCH, HD, 0, stream>>>(ctx0, ctx1, mean, score, fc1_w, fc1_b,
                                       fc2_w, fc2_b, out);
  k_profile<<<BATCH, HD, 0, stream>>>(efc1_w, efc1_b, efc2_w, efc2_b, out);
}